// Round 3
// baseline (268.590 us; speedup 1.0000x reference)
//
#include <hip/hip_runtime.h>
#include <hip/hip_fp16.h>
#include <math.h>

#define N_NODES 50000
#define N_EDGES 800000
#define D 128
#define BN_EPS 1e-5f
#define N_TILES 3125   // 50000 / 16

typedef __attribute__((ext_vector_type(8))) _Float16 half8;
typedef __attribute__((ext_vector_type(4))) float floatx4;

// ---------------- octonion Hamilton tables ----------------
// _OCT_TABLE[j][i] = (component, sign): H[i*16+k][j*16+m] = s * W[k][c*16+m]
__device__ __constant__ int OCT_C[8][8] = {
    {0,1,2,3,4,5,6,7},
    {1,0,3,2,5,4,7,6},
    {2,3,0,1,6,7,4,5},
    {3,2,1,0,7,6,5,4},
    {4,5,6,7,0,1,2,3},
    {5,4,7,6,1,0,3,2},
    {6,7,4,5,2,3,0,1},
    {7,6,5,4,3,2,1,0}};
__device__ __constant__ float OCT_S[8][8] = {
    { 1,-1,-1,-1,-1,-1,-1,-1},
    { 1, 1,-1, 1,-1, 1, 1,-1},
    { 1, 1, 1,-1,-1,-1, 1, 1},
    { 1,-1, 1, 1,-1, 1,-1, 1},
    { 1, 1, 1, 1, 1,-1,-1,-1},
    { 1,-1, 1,-1, 1, 1, 1,-1},
    { 1,-1,-1, 1, 1,-1, 1, 1},
    { 1, 1,-1,-1, 1, 1,-1, 1}};

// ---------------- CSR build ----------------

__global__ void zero_kernel(int* __restrict__ cnt, float* __restrict__ stats) {
    int i = blockIdx.x * 256 + threadIdx.x;
    if (i < N_NODES) cnt[i] = 0;
    if (i < 2 * D) stats[i] = 0.0f;
}

__global__ void count_kernel(const int* __restrict__ arow, int* __restrict__ cnt) {
    int i = blockIdx.x * 256 + threadIdx.x;
    if (i < N_EDGES) atomicAdd(&cnt[arow[i]], 1);
}

__global__ void scan_kernel(const int* __restrict__ cnt, int* __restrict__ rowptr,
                            int* __restrict__ rowcur) {
    const int tid = threadIdx.x;        // 1024 threads
    const int lane = tid & 63, wid = tid >> 6;  // 16 waves
    __shared__ int wtot[16];
    __shared__ int carry;
    if (tid == 0) carry = 0;
    __syncthreads();
    const int PER = 8;
    for (int start = 0; start < N_NODES; start += 1024 * PER) {
        int base_i = start + tid * PER;
        int v[PER];
        int s = 0;
#pragma unroll
        for (int j = 0; j < PER; ++j) {
            int i = base_i + j;
            v[j] = (i < N_NODES) ? cnt[i] : 0;
            s += v[j];
        }
        int incl = s;
#pragma unroll
        for (int off = 1; off < 64; off <<= 1) {
            int t = __shfl_up(incl, off, 64);
            if (lane >= off) incl += t;
        }
        if (lane == 63) wtot[wid] = incl;
        __syncthreads();
        if (tid == 0) {
            int acc = carry;
#pragma unroll
            for (int w = 0; w < 16; ++w) { int t = wtot[w]; wtot[w] = acc; acc += t; }
            carry = acc;
        }
        __syncthreads();
        int excl = wtot[wid] + (incl - s);
#pragma unroll
        for (int j = 0; j < PER; ++j) {
            int i = base_i + j;
            if (i < N_NODES) { rowptr[i] = excl; rowcur[i] = excl; }
            excl += v[j];
        }
        __syncthreads();
    }
    if (tid == 0) rowptr[N_NODES] = carry;
}

__global__ void scatter_kernel(const int* __restrict__ arow, const int* __restrict__ acol,
                               const float* __restrict__ aval, int* __restrict__ rowcur,
                               uint2* __restrict__ edata) {
    int i = blockIdx.x * 256 + threadIdx.x;
    if (i < N_EDGES) {
        int r = arow[i];
        int pos = atomicAdd(&rowcur[r], 1);
        edata[pos] = make_uint2((unsigned)acol[i], __float_as_uint(aval[i]));
    }
}

// ---------------- MFMA gemm: support(fp16) = fp16(input) @ fp16(H(W)) ----------------
// one 16-row tile per wave; B-fragments built from W via octonion table (no H materialization)
__global__ __launch_bounds__(256) void gemm_kernel(const float* __restrict__ in,
                                                   const float* __restrict__ W,
                                                   __half* __restrict__ support) {
    const int tid = threadIdx.x;
    const int wv = tid >> 6;
    const int lane = tid & 63;
    const int s = lane & 15;          // 0..15
    const int t = lane >> 4;          // 0..3

    // B-fragment b[n][kk]: lane holds H[kk*32 + 8t + j][16n + s], j=0..7
    // H row k: i = k>>4 = 2*kk + (t>>1); kw = k&15 = 8*(t&1) + j
    half8 b[8][4];
    const int kwbase = 8 * (t & 1);
    const int ibase = t >> 1;
#pragma unroll
    for (int kk = 0; kk < 4; ++kk) {
        const int i = 2 * kk + ibase;
#pragma unroll
        for (int n = 0; n < 8; ++n) {
            const int c = OCT_C[n][i];
            const float sgn = OCT_S[n][i];
            const float* wp = W + kwbase * D + c * 16 + s;
#pragma unroll
            for (int j = 0; j < 8; ++j)
                b[n][kk][j] = (_Float16)(sgn * wp[j * D]);
        }
    }

    const int tile = blockIdx.x * 4 + wv;
    if (tile >= N_TILES) return;

    // A-fragment: lane holds input[tile*16 + s][kk*32 + 8t + j]
    const float* ap = in + (size_t)(tile * 16 + s) * D;
    half8 a[4];
#pragma unroll
    for (int kk = 0; kk < 4; ++kk) {
        float4 f0 = *reinterpret_cast<const float4*>(ap + kk * 32 + 8 * t);
        float4 f1 = *reinterpret_cast<const float4*>(ap + kk * 32 + 8 * t + 4);
        a[kk][0] = (_Float16)f0.x; a[kk][1] = (_Float16)f0.y;
        a[kk][2] = (_Float16)f0.z; a[kk][3] = (_Float16)f0.w;
        a[kk][4] = (_Float16)f1.x; a[kk][5] = (_Float16)f1.y;
        a[kk][6] = (_Float16)f1.z; a[kk][7] = (_Float16)f1.w;
    }

    floatx4 acc[8];
#pragma unroll
    for (int n = 0; n < 8; ++n) acc[n] = (floatx4){0.f, 0.f, 0.f, 0.f};
#pragma unroll
    for (int kk = 0; kk < 4; ++kk)
#pragma unroll
        for (int n = 0; n < 8; ++n)
            acc[n] = __builtin_amdgcn_mfma_f32_16x16x32_f16(a[kk], b[n][kk], acc[n], 0, 0, 0);

    // D layout: col = 16n + s, row = 4t + r
    __half* sp = support + (size_t)(tile * 16 + 4 * t) * D + s;
#pragma unroll
    for (int r = 0; r < 4; ++r)
#pragma unroll
        for (int n = 0; n < 8; ++n)
            sp[(size_t)r * D + 16 * n] = __float2half(acc[n][r]);
}

// ---------------- CSR spmm: one row per 32-lane half-wave, half4/lane ----------------
__global__ __launch_bounds__(256) void spmm_kernel(const __half* __restrict__ support,
                                                   const int* __restrict__ rowptr,
                                                   const uint2* __restrict__ edata,
                                                   float* __restrict__ out,
                                                   float* __restrict__ colsum,
                                                   float* __restrict__ colsq) {
    const int tid = threadIdx.x;
    const int s = tid & 31;           // lane in half-wave
    const int slot = blockIdx.x * 8 + (tid >> 5);
    const int c4 = s * 4;             // column base

    float s0 = 0.f, s1 = 0.f, s2 = 0.f, s3 = 0.f;
    float q0 = 0.f, q1 = 0.f, q2 = 0.f, q3 = 0.f;

    for (int row = slot; row < N_NODES; row += gridDim.x * 8) {
        float a0 = 0.f, a1 = 0.f, a2 = 0.f, a3 = 0.f;
        const int e1 = rowptr[row + 1];
        int e = rowptr[row];
        for (; e + 4 <= e1; e += 4) {
            uint2 d0 = edata[e + 0], d1 = edata[e + 1], d2 = edata[e + 2], d3 = edata[e + 3];
            uint2 r0 = *reinterpret_cast<const uint2*>(support + (size_t)d0.x * D + c4);
            uint2 r1 = *reinterpret_cast<const uint2*>(support + (size_t)d1.x * D + c4);
            uint2 r2 = *reinterpret_cast<const uint2*>(support + (size_t)d2.x * D + c4);
            uint2 r3 = *reinterpret_cast<const uint2*>(support + (size_t)d3.x * D + c4);
            float v0 = __uint_as_float(d0.y), v1 = __uint_as_float(d1.y);
            float v2 = __uint_as_float(d2.y), v3 = __uint_as_float(d3.y);
            float2 f;
            f = __half22float2(*reinterpret_cast<__half2*>(&r0.x)); a0 += v0 * f.x; a1 += v0 * f.y;
            f = __half22float2(*reinterpret_cast<__half2*>(&r0.y)); a2 += v0 * f.x; a3 += v0 * f.y;
            f = __half22float2(*reinterpret_cast<__half2*>(&r1.x)); a0 += v1 * f.x; a1 += v1 * f.y;
            f = __half22float2(*reinterpret_cast<__half2*>(&r1.y)); a2 += v1 * f.x; a3 += v1 * f.y;
            f = __half22float2(*reinterpret_cast<__half2*>(&r2.x)); a0 += v2 * f.x; a1 += v2 * f.y;
            f = __half22float2(*reinterpret_cast<__half2*>(&r2.y)); a2 += v2 * f.x; a3 += v2 * f.y;
            f = __half22float2(*reinterpret_cast<__half2*>(&r3.x)); a0 += v3 * f.x; a1 += v3 * f.y;
            f = __half22float2(*reinterpret_cast<__half2*>(&r3.y)); a2 += v3 * f.x; a3 += v3 * f.y;
        }
        for (; e < e1; ++e) {
            uint2 d0 = edata[e];
            uint2 r0 = *reinterpret_cast<const uint2*>(support + (size_t)d0.x * D + c4);
            float v0 = __uint_as_float(d0.y);
            float2 f;
            f = __half22float2(*reinterpret_cast<__half2*>(&r0.x)); a0 += v0 * f.x; a1 += v0 * f.y;
            f = __half22float2(*reinterpret_cast<__half2*>(&r0.y)); a2 += v0 * f.x; a3 += v0 * f.y;
        }
        *reinterpret_cast<float4*>(out + (size_t)row * D + c4) = make_float4(a0, a1, a2, a3);
        s0 += a0; s1 += a1; s2 += a2; s3 += a3;
        q0 += a0 * a0; q1 += a1 * a1; q2 += a2 * a2; q3 += a3 * a3;
    }

    __shared__ float lsum[D], lsq[D];
    if (tid < D) { lsum[tid] = 0.f; lsq[tid] = 0.f; }
    __syncthreads();
    atomicAdd(&lsum[c4 + 0], s0); atomicAdd(&lsum[c4 + 1], s1);
    atomicAdd(&lsum[c4 + 2], s2); atomicAdd(&lsum[c4 + 3], s3);
    atomicAdd(&lsq[c4 + 0], q0);  atomicAdd(&lsq[c4 + 1], q1);
    atomicAdd(&lsq[c4 + 2], q2);  atomicAdd(&lsq[c4 + 3], q3);
    __syncthreads();
    if (tid < D) {
        atomicAdd(&colsum[tid], lsum[tid]);
        atomicAdd(&colsq[tid], lsq[tid]);
    }
}

__global__ __launch_bounds__(256) void bn_tanh_kernel(float* __restrict__ out,
                                                      const float* __restrict__ colsum,
                                                      const float* __restrict__ colsq,
                                                      const float* __restrict__ gamma,
                                                      const float* __restrict__ beta) {
    __shared__ float scale[D], shift[D];
    const int tid = threadIdx.x;
    if (tid < D) {
        float mean = colsum[tid] * (1.0f / N_NODES);
        float var  = colsq[tid] * (1.0f / N_NODES) - mean * mean;
        float sc   = rsqrtf(var + BN_EPS) * gamma[tid];
        scale[tid] = sc;
        shift[tid] = beta[tid] - mean * sc;
    }
    __syncthreads();
    const int nq = N_NODES * D / 4;
    for (int q = blockIdx.x * 256 + tid; q < nq; q += gridDim.x * 256) {
        float4 v = reinterpret_cast<float4*>(out)[q];
        int c = (q & 31) * 4;
        v.x = tanhf(v.x * scale[c + 0] + shift[c + 0]);
        v.y = tanhf(v.y * scale[c + 1] + shift[c + 1]);
        v.z = tanhf(v.z * scale[c + 2] + shift[c + 2]);
        v.w = tanhf(v.w * scale[c + 3] + shift[c + 3]);
        reinterpret_cast<float4*>(out)[q] = v;
    }
}

// ---------------- launch ----------------
extern "C" void kernel_launch(void* const* d_in, const int* in_sizes, int n_in,
                              void* d_out, int out_size, void* d_ws, size_t ws_size,
                              hipStream_t stream) {
    const float* input  = (const float*)d_in[0];
    const int*   arow   = (const int*)d_in[1];
    const int*   acol   = (const int*)d_in[2];
    const float* aval   = (const float*)d_in[3];
    const float* weight = (const float*)d_in[4];
    const float* gamma  = (const float*)d_in[5];
    const float* beta   = (const float*)d_in[6];
    float* out = (float*)d_out;

    __half* support = (__half*)d_ws;                           // 6.4M halfs (12.8 MB)
    uint2*  edata   = (uint2*)(support + (size_t)N_NODES * D); // 800000 * 8 B
    int*    cnt     = (int*)(edata + N_EDGES);                 // 50000
    int*    rowptr  = cnt + N_NODES;                           // 50001
    int*    rowcur  = rowptr + (N_NODES + 1);                  // 50000
    float*  colsum  = (float*)(rowcur + N_NODES);              // 128 (+128 colsq)

    zero_kernel<<<196, 256, 0, stream>>>(cnt, colsum);
    count_kernel<<<N_EDGES / 256, 256, 0, stream>>>(arow, cnt);
    scan_kernel<<<1, 1024, 0, stream>>>(cnt, rowptr, rowcur);
    scatter_kernel<<<N_EDGES / 256, 256, 0, stream>>>(arow, acol, aval, rowcur, edata);
    gemm_kernel<<<(N_TILES + 3) / 4, 256, 0, stream>>>(input, weight, support);
    spmm_kernel<<<N_TILES, 256, 0, stream>>>(support, rowptr, edata, out, colsum, colsum + D);
    bn_tanh_kernel<<<2048, 256, 0, stream>>>(out, colsum, colsum + D, gamma, beta);
}

// Round 4
// 180.015 us; speedup vs baseline: 1.4920x; 1.4920x over previous
//
#include <hip/hip_runtime.h>
#include <hip/hip_fp16.h>
#include <math.h>

#define N_NODES 50000
#define N_EDGES 800000
#define D 128
#define BN_EPS 1e-5f
#define N_TILES 3125   // 50000 / 16
#define CAP 64         // max degree capacity (Poisson(16); P(deg>64) ~ 1e-19)

typedef __attribute__((ext_vector_type(8))) _Float16 half8;
typedef __attribute__((ext_vector_type(4))) float floatx4;

// ---------------- octonion Hamilton tables ----------------
// _OCT_TABLE[j][i] = (component, sign): H[i*16+k][j*16+m] = s * W[k][c*16+m]
__device__ __constant__ int OCT_C[8][8] = {
    {0,1,2,3,4,5,6,7},
    {1,0,3,2,5,4,7,6},
    {2,3,0,1,6,7,4,5},
    {3,2,1,0,7,6,5,4},
    {4,5,6,7,0,1,2,3},
    {5,4,7,6,1,0,3,2},
    {6,7,4,5,2,3,0,1},
    {7,6,5,4,3,2,1,0}};
__device__ __constant__ float OCT_S[8][8] = {
    { 1,-1,-1,-1,-1,-1,-1,-1},
    { 1, 1,-1, 1,-1, 1, 1,-1},
    { 1, 1, 1,-1,-1,-1, 1, 1},
    { 1,-1, 1, 1,-1, 1,-1, 1},
    { 1, 1, 1, 1, 1,-1,-1,-1},
    { 1,-1, 1,-1, 1, 1, 1,-1},
    { 1,-1,-1, 1, 1,-1, 1, 1},
    { 1, 1,-1,-1, 1, 1,-1, 1}};

// ---------------- kernels ----------------

__global__ void zero_kernel(int* __restrict__ cnt, float* __restrict__ stats) {
    int i = blockIdx.x * 256 + threadIdx.x;
    if (i < N_NODES) cnt[i] = 0;
    if (i < 2 * D) stats[i] = 0.0f;
}

// bucket scatter: edge -> (col:u16 | half(val):u16) in bucket[row*CAP + slot]
__global__ void scatter_kernel(const int* __restrict__ arow, const int* __restrict__ acol,
                               const float* __restrict__ aval, int* __restrict__ cnt,
                               unsigned* __restrict__ bucket) {
    int i = blockIdx.x * 256 + threadIdx.x;
    if (i < N_EDGES) {
        int r = arow[i];
        int slot = atomicAdd(&cnt[r], 1);
        if (slot < CAP) {
            unsigned hv = (unsigned)__half_as_ushort(__float2half(aval[i]));
            bucket[r * CAP + slot] = ((unsigned)acol[i] & 0xFFFFu) | (hv << 16);
        }
    }
}

// ---------------- MFMA gemm: support(fp16) = fp16(input) @ fp16(H(W)) ----------------
__global__ __launch_bounds__(256) void gemm_kernel(const float* __restrict__ in,
                                                   const float* __restrict__ W,
                                                   __half* __restrict__ support) {
    const int tid = threadIdx.x;
    const int wv = tid >> 6;
    const int lane = tid & 63;
    const int s = lane & 15;          // 0..15
    const int t = lane >> 4;          // 0..3

    // B-fragment b[n][kk]: lane holds H[kk*32 + 8t + j][16n + s], j=0..7
    half8 b[8][4];
    const int kwbase = 8 * (t & 1);
    const int ibase = t >> 1;
#pragma unroll
    for (int kk = 0; kk < 4; ++kk) {
        const int i = 2 * kk + ibase;
#pragma unroll
        for (int n = 0; n < 8; ++n) {
            const int c = OCT_C[n][i];
            const float sgn = OCT_S[n][i];
            const float* wp = W + kwbase * D + c * 16 + s;
#pragma unroll
            for (int j = 0; j < 8; ++j)
                b[n][kk][j] = (_Float16)(sgn * wp[j * D]);
        }
    }

    const int tile = blockIdx.x * 4 + wv;
    if (tile >= N_TILES) return;

    const float* ap = in + (size_t)(tile * 16 + s) * D;
    half8 a[4];
#pragma unroll
    for (int kk = 0; kk < 4; ++kk) {
        float4 f0 = *reinterpret_cast<const float4*>(ap + kk * 32 + 8 * t);
        float4 f1 = *reinterpret_cast<const float4*>(ap + kk * 32 + 8 * t + 4);
        a[kk][0] = (_Float16)f0.x; a[kk][1] = (_Float16)f0.y;
        a[kk][2] = (_Float16)f0.z; a[kk][3] = (_Float16)f0.w;
        a[kk][4] = (_Float16)f1.x; a[kk][5] = (_Float16)f1.y;
        a[kk][6] = (_Float16)f1.z; a[kk][7] = (_Float16)f1.w;
    }

    floatx4 acc[8];
#pragma unroll
    for (int n = 0; n < 8; ++n) acc[n] = (floatx4){0.f, 0.f, 0.f, 0.f};
#pragma unroll
    for (int kk = 0; kk < 4; ++kk)
#pragma unroll
        for (int n = 0; n < 8; ++n)
            acc[n] = __builtin_amdgcn_mfma_f32_16x16x32_f16(a[kk], b[n][kk], acc[n], 0, 0, 0);

    // D layout: col = 16n + s, row = 4t + r
    __half* sp = support + (size_t)(tile * 16 + 4 * t) * D + s;
#pragma unroll
    for (int r = 0; r < 4; ++r)
#pragma unroll
        for (int n = 0; n < 8; ++n)
            sp[(size_t)r * D + 16 * n] = __float2half(acc[n][r]);
}

// ---------------- bucket spmm: one 64-lane wave per row, half2/lane ----------------
// lane i holds edge i's packed word; __shfl broadcasts -> no dependent edata loads.
__global__ __launch_bounds__(256) void spmm_kernel(const __half* __restrict__ support,
                                                   const int* __restrict__ cnt,
                                                   const unsigned* __restrict__ bucket,
                                                   float* __restrict__ out,
                                                   float* __restrict__ colsum,
                                                   float* __restrict__ colsq) {
    const int tid = threadIdx.x;
    const int lane = tid & 63;
    const int wv = tid >> 6;
    const int c2 = lane * 2;

    float s0 = 0.f, s1 = 0.f, q0 = 0.f, q1 = 0.f;

    for (int row = blockIdx.x * 4 + wv; row < N_NODES; row += gridDim.x * 4) {
        int n = cnt[row];
        n = n < CAP ? n : CAP;
        const unsigned ew = bucket[(size_t)row * CAP + lane];   // one 256B load
        float a0 = 0.f, a1 = 0.f;
        const int n8 = (n + 7) & ~7;
        for (int e = 0; e < n8; e += 8) {
            unsigned u[8];
#pragma unroll
            for (int j = 0; j < 8; ++j) {
                int idx = e + j;
                unsigned w = __shfl(ew, idx < 63 ? idx : 63);
                u[j] = (idx < n) ? w : 0u;
            }
            __half2 g[8];
#pragma unroll
            for (int j = 0; j < 8; ++j)
                g[j] = *reinterpret_cast<const __half2*>(support + (size_t)(u[j] & 0xFFFFu) * D + c2);
#pragma unroll
            for (int j = 0; j < 8; ++j) {
                float v = __half2float(__ushort_as_half((unsigned short)(u[j] >> 16)));
                float2 f = __half22float2(g[j]);
                a0 += v * f.x;
                a1 += v * f.y;
            }
        }
        *reinterpret_cast<float2*>(out + (size_t)row * D + c2) = make_float2(a0, a1);
        s0 += a0; s1 += a1;
        q0 += a0 * a0; q1 += a1 * a1;
    }

    __shared__ float lsum[D], lsq[D];
    if (tid < D) { lsum[tid] = 0.f; lsq[tid] = 0.f; }
    __syncthreads();
    atomicAdd(&lsum[c2 + 0], s0); atomicAdd(&lsum[c2 + 1], s1);
    atomicAdd(&lsq[c2 + 0], q0);  atomicAdd(&lsq[c2 + 1], q1);
    __syncthreads();
    if (tid < D) {
        atomicAdd(&colsum[tid], lsum[tid]);
        atomicAdd(&colsq[tid], lsq[tid]);
    }
}

__global__ __launch_bounds__(256) void bn_tanh_kernel(float* __restrict__ out,
                                                      const float* __restrict__ colsum,
                                                      const float* __restrict__ colsq,
                                                      const float* __restrict__ gamma,
                                                      const float* __restrict__ beta) {
    __shared__ float scale[D], shift[D];
    const int tid = threadIdx.x;
    if (tid < D) {
        float mean = colsum[tid] * (1.0f / N_NODES);
        float var  = colsq[tid] * (1.0f / N_NODES) - mean * mean;
        float sc   = rsqrtf(var + BN_EPS) * gamma[tid];
        scale[tid] = sc;
        shift[tid] = beta[tid] - mean * sc;
    }
    __syncthreads();
    const int nq = N_NODES * D / 4;
    for (int q = blockIdx.x * 256 + tid; q < nq; q += gridDim.x * 256) {
        float4 v = reinterpret_cast<float4*>(out)[q];
        int c = (q & 31) * 4;
#pragma unroll
        for (int k = 0; k < 4; ++k) {
            float* pv = (&v.x) + k;
            float x = *pv * scale[c + k] + shift[c + k];
            float e = __expf(2.0f * x);
            *pv = 1.0f - 2.0f / (1.0f + e);
        }
        reinterpret_cast<float4*>(out)[q] = v;
    }
}

// ---------------- launch ----------------
extern "C" void kernel_launch(void* const* d_in, const int* in_sizes, int n_in,
                              void* d_out, int out_size, void* d_ws, size_t ws_size,
                              hipStream_t stream) {
    const float* input  = (const float*)d_in[0];
    const int*   arow   = (const int*)d_in[1];
    const int*   acol   = (const int*)d_in[2];
    const float* aval   = (const float*)d_in[3];
    const float* weight = (const float*)d_in[4];
    const float* gamma  = (const float*)d_in[5];
    const float* beta   = (const float*)d_in[6];
    float* out = (float*)d_out;

    __half*   support = (__half*)d_ws;                            // 12.8 MB
    unsigned* bucket  = (unsigned*)(support + (size_t)N_NODES * D); // 12.8 MB
    int*      cnt     = (int*)(bucket + (size_t)N_NODES * CAP);   // 200 KB
    float*    colsum  = (float*)(cnt + N_NODES);                  // 128 (+128 colsq)

    zero_kernel<<<196, 256, 0, stream>>>(cnt, colsum);
    scatter_kernel<<<N_EDGES / 256, 256, 0, stream>>>(arow, acol, aval, cnt, bucket);
    gemm_kernel<<<(N_TILES + 3) / 4, 256, 0, stream>>>(input, weight, support);
    spmm_kernel<<<N_TILES, 256, 0, stream>>>(support, cnt, bucket, out, colsum, colsum + D);
    bn_tanh_kernel<<<2048, 256, 0, stream>>>(out, colsum, colsum + D, gamma, beta);
}

// Round 5
// 178.039 us; speedup vs baseline: 1.5086x; 1.0111x over previous
//
#include <hip/hip_runtime.h>
#include <hip/hip_fp16.h>
#include <math.h>

#define N_NODES 50000
#define N_EDGES 800000
#define D 128
#define BN_EPS 1e-5f
#define N_TILES 3125   // 50000 / 16
#define CAP 64         // max degree capacity (Poisson(16); P(deg>64) ~ 1e-19)
#define CHUNKS 4
#define CCOLS 32       // columns per chunk (3.2 MB fp16 slice -> fits 4 MiB L2)
#define SPMM_BLOCKS 2048

typedef __attribute__((ext_vector_type(8))) _Float16 half8;
typedef __attribute__((ext_vector_type(4))) float floatx4;

// ---------------- octonion Hamilton tables ----------------
// _OCT_TABLE[j][i] = (component, sign): H[i*16+k][j*16+m] = s * W[k][c*16+m]
__device__ __constant__ int OCT_C[8][8] = {
    {0,1,2,3,4,5,6,7},
    {1,0,3,2,5,4,7,6},
    {2,3,0,1,6,7,4,5},
    {3,2,1,0,7,6,5,4},
    {4,5,6,7,0,1,2,3},
    {5,4,7,6,1,0,3,2},
    {6,7,4,5,2,3,0,1},
    {7,6,5,4,3,2,1,0}};
__device__ __constant__ float OCT_S[8][8] = {
    { 1,-1,-1,-1,-1,-1,-1,-1},
    { 1, 1,-1, 1,-1, 1, 1,-1},
    { 1, 1, 1,-1,-1,-1, 1, 1},
    { 1,-1, 1, 1,-1, 1,-1, 1},
    { 1, 1, 1, 1, 1,-1,-1,-1},
    { 1,-1, 1,-1, 1, 1, 1,-1},
    { 1,-1,-1, 1, 1,-1, 1, 1},
    { 1, 1,-1,-1, 1, 1,-1, 1}};

// ---------------- kernels ----------------

__global__ void zero_kernel(int* __restrict__ cnt, float* __restrict__ stats) {
    int i = blockIdx.x * 256 + threadIdx.x;
    if (i < N_NODES) cnt[i] = 0;
    if (i < 2 * D) stats[i] = 0.0f;
}

// Ht[col][k] = H[k][col] in fp16 (transposed Hamilton, 32 KB)
__global__ void buildht_kernel(const float* __restrict__ W, __half* __restrict__ Ht) {
    int idx = blockIdx.x * 256 + threadIdx.x;   // 16384
    int ccol = idx >> 7, k = idx & 127;
    int i = k >> 4, kw = k & 15, j = ccol >> 4, m = ccol & 15;
    Ht[idx] = __float2half(OCT_S[j][i] * W[kw * D + OCT_C[j][i] * 16 + m]);
}

// bucket scatter: edge -> (col:u16 | half(val):u16) in bucket[row*CAP + slot]
__global__ void scatter_kernel(const int* __restrict__ arow, const int* __restrict__ acol,
                               const float* __restrict__ aval, int* __restrict__ cnt,
                               unsigned* __restrict__ bucket) {
    int i = blockIdx.x * 256 + threadIdx.x;
    if (i < N_EDGES) {
        int r = arow[i];
        int slot = atomicAdd(&cnt[r], 1);
        if (slot < CAP) {
            unsigned hv = (unsigned)__half_as_ushort(__float2half(aval[i]));
            bucket[r * CAP + slot] = ((unsigned)acol[i] & 0xFFFFu) | (hv << 16);
        }
    }
}

// ---------------- MFMA gemm: support(fp16) = fp16(input) @ Ht^T ----------------
__global__ __launch_bounds__(256) void gemm_kernel(const float* __restrict__ in,
                                                   const __half* __restrict__ Ht,
                                                   __half* __restrict__ support) {
    const int tid = threadIdx.x;
    const int wv = tid >> 6;
    const int lane = tid & 63;
    const int s = lane & 15;          // 0..15
    const int t = lane >> 4;          // 0..3

    // B-fragment b[n][kk]: lane holds H[kk*32 + 8t + j][16n + s] = Ht[16n+s][kk*32+8t+j]
    half8 b[8][4];
#pragma unroll
    for (int kk = 0; kk < 4; ++kk)
#pragma unroll
        for (int n = 0; n < 8; ++n)
            b[n][kk] = *reinterpret_cast<const half8*>(Ht + (size_t)(16 * n + s) * D + kk * 32 + 8 * t);

    const int tile = blockIdx.x * 4 + wv;
    if (tile >= N_TILES) return;

    // A-fragment: lane holds input[tile*16 + s][kk*32 + 8t + j]
    const float* ap = in + (size_t)(tile * 16 + s) * D;
    half8 a[4];
#pragma unroll
    for (int kk = 0; kk < 4; ++kk) {
        float4 f0 = *reinterpret_cast<const float4*>(ap + kk * 32 + 8 * t);
        float4 f1 = *reinterpret_cast<const float4*>(ap + kk * 32 + 8 * t + 4);
        a[kk][0] = (_Float16)f0.x; a[kk][1] = (_Float16)f0.y;
        a[kk][2] = (_Float16)f0.z; a[kk][3] = (_Float16)f0.w;
        a[kk][4] = (_Float16)f1.x; a[kk][5] = (_Float16)f1.y;
        a[kk][6] = (_Float16)f1.z; a[kk][7] = (_Float16)f1.w;
    }

    floatx4 acc[8];
#pragma unroll
    for (int n = 0; n < 8; ++n) acc[n] = (floatx4){0.f, 0.f, 0.f, 0.f};
#pragma unroll
    for (int kk = 0; kk < 4; ++kk)
#pragma unroll
        for (int n = 0; n < 8; ++n)
            acc[n] = __builtin_amdgcn_mfma_f32_16x16x32_f16(a[kk], b[n][kk], acc[n], 0, 0, 0);

    // D layout: col = 16n + s, row = 4t + r
    __half* sp = support + (size_t)(tile * 16 + 4 * t) * D + s;
#pragma unroll
    for (int r = 0; r < 4; ++r)
#pragma unroll
        for (int n = 0; n < 8; ++n)
            sp[(size_t)r * D + 16 * n] = __float2half(acc[n][r]);
}

// ---------------- chunked bucket spmm ----------------
// Each block loops the 4 column chunks internally so one 3.2 MB support slice
// is L2-hot at a time. Wave = 4 groups of 16 lanes; group h gathers edge e+4j+h's
// 64 B slice -> 16 independent gathers in flight; shfl_xor(16/32) combines groups.
__global__ __launch_bounds__(256) void spmm_kernel(const __half* __restrict__ support,
                                                   const int* __restrict__ cnt,
                                                   const unsigned* __restrict__ bucket,
                                                   float* __restrict__ out,
                                                   float* __restrict__ colsum,
                                                   float* __restrict__ colsq) {
    const int tid = threadIdx.x;
    const int lane = tid & 63;
    const int wv = tid >> 6;
    const int h = lane >> 4;          // edge group 0..3
    const int cl = lane & 15;         // column lane
    const int slot = blockIdx.x * 4 + wv;

    __shared__ float lsum[D], lsq[D];
    if (tid < D) { lsum[tid] = 0.f; lsq[tid] = 0.f; }
    __syncthreads();

    for (int c = 0; c < CHUNKS; ++c) {
        const int colbase = c * CCOLS + cl * 2;
        float s0 = 0.f, s1 = 0.f, q0 = 0.f, q1 = 0.f;
        for (int row = slot; row < N_NODES; row += SPMM_BLOCKS * 4) {
            int n = cnt[row];
            n = n < CAP ? n : CAP;
            const unsigned ew = bucket[(size_t)row * CAP + lane];   // 256 B / wave
            float a0 = 0.f, a1 = 0.f;
            const int n16 = (n + 15) & ~15;
            for (int e = 0; e < n16; e += 16) {
                unsigned u[4];
                __half2 g[4];
#pragma unroll
                for (int j = 0; j < 4; ++j) {
                    int idx = e + j * 4 + h;
                    unsigned w = __shfl(ew, idx);
                    u[j] = (idx < n) ? w : 0u;
                }
#pragma unroll
                for (int j = 0; j < 4; ++j)
                    g[j] = *reinterpret_cast<const __half2*>(support + (size_t)(u[j] & 0xFFFFu) * D + colbase);
#pragma unroll
                for (int j = 0; j < 4; ++j) {
                    float v = __half2float(__ushort_as_half((unsigned short)(u[j] >> 16)));
                    float2 f = __half22float2(g[j]);
                    a0 += v * f.x;
                    a1 += v * f.y;
                }
            }
            // combine the 4 edge groups (same columns, disjoint edges)
            a0 += __shfl_xor(a0, 16); a1 += __shfl_xor(a1, 16);
            a0 += __shfl_xor(a0, 32); a1 += __shfl_xor(a1, 32);
            if (h == 0) {
                *reinterpret_cast<float2*>(out + (size_t)row * D + colbase) = make_float2(a0, a1);
                s0 += a0; s1 += a1;
                q0 += a0 * a0; q1 += a1 * a1;
            }
        }
        if (h == 0) {
            atomicAdd(&lsum[colbase + 0], s0); atomicAdd(&lsum[colbase + 1], s1);
            atomicAdd(&lsq[colbase + 0], q0);  atomicAdd(&lsq[colbase + 1], q1);
        }
    }
    __syncthreads();
    if (tid < D) {
        atomicAdd(&colsum[tid], lsum[tid]);
        atomicAdd(&colsq[tid], lsq[tid]);
    }
}

__global__ __launch_bounds__(256) void bn_tanh_kernel(float* __restrict__ out,
                                                      const float* __restrict__ colsum,
                                                      const float* __restrict__ colsq,
                                                      const float* __restrict__ gamma,
                                                      const float* __restrict__ beta) {
    __shared__ float scale[D], shift[D];
    const int tid = threadIdx.x;
    if (tid < D) {
        float mean = colsum[tid] * (1.0f / N_NODES);
        float var  = colsq[tid] * (1.0f / N_NODES) - mean * mean;
        float sc   = rsqrtf(var + BN_EPS) * gamma[tid];
        scale[tid] = sc;
        shift[tid] = beta[tid] - mean * sc;
    }
    __syncthreads();
    const int nq = N_NODES * D / 4;
    for (int q = blockIdx.x * 256 + tid; q < nq; q += gridDim.x * 256) {
        float4 v = reinterpret_cast<float4*>(out)[q];
        int c = (q & 31) * 4;
#pragma unroll
        for (int k = 0; k < 4; ++k) {
            float* pv = (&v.x) + k;
            float x = *pv * scale[c + k] + shift[c + k];
            float e = __expf(2.0f * x);
            *pv = 1.0f - 2.0f / (1.0f + e);
        }
        reinterpret_cast<float4*>(out)[q] = v;
    }
}

// ---------------- launch ----------------
extern "C" void kernel_launch(void* const* d_in, const int* in_sizes, int n_in,
                              void* d_out, int out_size, void* d_ws, size_t ws_size,
                              hipStream_t stream) {
    const float* input  = (const float*)d_in[0];
    const int*   arow   = (const int*)d_in[1];
    const int*   acol   = (const int*)d_in[2];
    const float* aval   = (const float*)d_in[3];
    const float* weight = (const float*)d_in[4];
    const float* gamma  = (const float*)d_in[5];
    const float* beta   = (const float*)d_in[6];
    float* out = (float*)d_out;

    __half*   support = (__half*)d_ws;                              // 12.8 MB
    unsigned* bucket  = (unsigned*)(support + (size_t)N_NODES * D); // 12.8 MB
    int*      cnt     = (int*)(bucket + (size_t)N_NODES * CAP);     // 200 KB
    float*    colsum  = (float*)(cnt + N_NODES);                    // 128 (+128 colsq)
    __half*   Ht      = (__half*)(colsum + 2 * D);                  // 32 KB

    zero_kernel<<<196, 256, 0, stream>>>(cnt, colsum);
    buildht_kernel<<<64, 256, 0, stream>>>(weight, Ht);
    scatter_kernel<<<N_EDGES / 256, 256, 0, stream>>>(arow, acol, aval, cnt, bucket);
    gemm_kernel<<<(N_TILES + 3) / 4, 256, 0, stream>>>(input, Ht, support);
    spmm_kernel<<<SPMM_BLOCKS, 256, 0, stream>>>(support, cnt, bucket, out, colsum, colsum + D);
    bn_tanh_kernel<<<2048, 256, 0, stream>>>(out, colsum, colsum + D, gamma, beta);
}

// Round 6
// 134.572 us; speedup vs baseline: 1.9959x; 1.3230x over previous
//
#include <hip/hip_runtime.h>
#include <hip/hip_fp16.h>
#include <math.h>

#define N_NODES 50000
#define N_EDGES 800000
#define D 128
#define BN_EPS 1e-5f
#define N_TILES 3125   // 50000 / 16
#define CAP 64         // max degree capacity (Poisson(16); P(deg>64) ~ 1e-19)
#define SPMM_BLOCKS 2048
#define SCOLS 32       // columns per XCD-pinned slice (3.2 MB fp16 -> fits 4 MiB L2)

typedef __attribute__((ext_vector_type(8))) _Float16 half8;
typedef __attribute__((ext_vector_type(4))) float floatx4;

// ---------------- octonion Hamilton tables ----------------
__device__ __constant__ int OCT_C[8][8] = {
    {0,1,2,3,4,5,6,7},
    {1,0,3,2,5,4,7,6},
    {2,3,0,1,6,7,4,5},
    {3,2,1,0,7,6,5,4},
    {4,5,6,7,0,1,2,3},
    {5,4,7,6,1,0,3,2},
    {6,7,4,5,2,3,0,1},
    {7,6,5,4,3,2,1,0}};
__device__ __constant__ float OCT_S[8][8] = {
    { 1,-1,-1,-1,-1,-1,-1,-1},
    { 1, 1,-1, 1,-1, 1, 1,-1},
    { 1, 1, 1,-1,-1,-1, 1, 1},
    { 1,-1, 1, 1,-1, 1,-1, 1},
    { 1, 1, 1, 1, 1,-1,-1,-1},
    { 1,-1, 1,-1, 1, 1, 1,-1},
    { 1,-1,-1, 1, 1,-1, 1, 1},
    { 1, 1,-1,-1, 1, 1,-1, 1}};

// ---------------- kernels ----------------

__global__ void zero_kernel(int* __restrict__ cnt, float* __restrict__ stats) {
    int i = blockIdx.x * 256 + threadIdx.x;
    if (i < N_NODES) cnt[i] = 0;
    if (i < 2 * D) stats[i] = 0.0f;
}

// Ht[col][k] = H[k][col] in fp16 (transposed Hamilton, 32 KB)
__global__ void buildht_kernel(const float* __restrict__ W, __half* __restrict__ Ht) {
    int idx = blockIdx.x * 256 + threadIdx.x;   // 16384
    int ccol = idx >> 7, k = idx & 127;
    int i = k >> 4, kw = k & 15, j = ccol >> 4, m = ccol & 15;
    Ht[idx] = __float2half(OCT_S[j][i] * W[kw * D + OCT_C[j][i] * 16 + m]);
}

// bucket scatter: edge -> (col:u16 | half(val):u16) in bucket[row*CAP + slot]
__global__ void scatter_kernel(const int* __restrict__ arow, const int* __restrict__ acol,
                               const float* __restrict__ aval, int* __restrict__ cnt,
                               unsigned* __restrict__ bucket) {
    int i = blockIdx.x * 256 + threadIdx.x;
    if (i < N_EDGES) {
        int r = arow[i];
        int slot = atomicAdd(&cnt[r], 1);
        if (slot < CAP) {
            unsigned hv = (unsigned)__half_as_ushort(__float2half(aval[i]));
            bucket[r * CAP + slot] = ((unsigned)acol[i] & 0xFFFFu) | (hv << 16);
        }
    }
}

// ---------------- MFMA gemm: support(fp16) = fp16(input) @ Ht^T ----------------
__global__ __launch_bounds__(256) void gemm_kernel(const float* __restrict__ in,
                                                   const __half* __restrict__ Ht,
                                                   __half* __restrict__ support) {
    const int tid = threadIdx.x;
    const int wv = tid >> 6;
    const int lane = tid & 63;
    const int s = lane & 15;
    const int t = lane >> 4;

    half8 b[8][4];
#pragma unroll
    for (int kk = 0; kk < 4; ++kk)
#pragma unroll
        for (int n = 0; n < 8; ++n)
            b[n][kk] = *reinterpret_cast<const half8*>(Ht + (size_t)(16 * n + s) * D + kk * 32 + 8 * t);

    const int tile = blockIdx.x * 4 + wv;
    if (tile >= N_TILES) return;

    const float* ap = in + (size_t)(tile * 16 + s) * D;
    half8 a[4];
#pragma unroll
    for (int kk = 0; kk < 4; ++kk) {
        float4 f0 = *reinterpret_cast<const float4*>(ap + kk * 32 + 8 * t);
        float4 f1 = *reinterpret_cast<const float4*>(ap + kk * 32 + 8 * t + 4);
        a[kk][0] = (_Float16)f0.x; a[kk][1] = (_Float16)f0.y;
        a[kk][2] = (_Float16)f0.z; a[kk][3] = (_Float16)f0.w;
        a[kk][4] = (_Float16)f1.x; a[kk][5] = (_Float16)f1.y;
        a[kk][6] = (_Float16)f1.z; a[kk][7] = (_Float16)f1.w;
    }

    floatx4 acc[8];
#pragma unroll
    for (int n = 0; n < 8; ++n) acc[n] = (floatx4){0.f, 0.f, 0.f, 0.f};
#pragma unroll
    for (int kk = 0; kk < 4; ++kk)
#pragma unroll
        for (int n = 0; n < 8; ++n)
            acc[n] = __builtin_amdgcn_mfma_f32_16x16x32_f16(a[kk], b[n][kk], acc[n], 0, 0, 0);

    __half* sp = support + (size_t)(tile * 16 + 4 * t) * D + s;
#pragma unroll
    for (int r = 0; r < 4; ++r)
#pragma unroll
        for (int n = 0; n < 8; ++n)
            sp[(size_t)r * D + 16 * n] = __float2half(acc[n][r]);
}

// ---------------- XCD-sliced bucket spmm ----------------
// slice = (blockIdx&7)>>1: consecutive blocks round-robin XCDs, so each XCD pair
// works one 32-col slice -> its 3.2 MB support slab stays L2-resident all kernel.
// Wave = 4 groups of 16 lanes; 2 rows in flight -> 8 independent gathers.
__global__ __launch_bounds__(256) void spmm_kernel(const __half* __restrict__ support,
                                                   const int* __restrict__ cnt,
                                                   const unsigned* __restrict__ bucket,
                                                   float* __restrict__ out,
                                                   float* __restrict__ colsum,
                                                   float* __restrict__ colsq) {
    const int tid = threadIdx.x;
    const int lane = tid & 63;
    const int wv = tid >> 6;
    const int h = lane >> 4;          // edge group 0..3
    const int cl = lane & 15;         // column lane
    const int b = blockIdx.x;
    const int slice = (b & 7) >> 1;
    const int rank = ((b >> 3) << 1) | (b & 1);   // 0..511 within slice
    const int nrank = SPMM_BLOCKS >> 2;           // 512
    const int colbase = slice * SCOLS + cl * 2;

    __shared__ float lsum[SCOLS], lsq[SCOLS];
    if (tid < SCOLS) { lsum[tid] = 0.f; lsq[tid] = 0.f; }
    __syncthreads();

    float s0 = 0.f, s1 = 0.f, q0 = 0.f, q1 = 0.f;

    for (int row = rank * 8 + wv * 2; row < N_NODES; row += nrank * 8) {
        const int rowb = row + 1;
        int na = cnt[row]; na = na < CAP ? na : CAP;
        int nb = (rowb < N_NODES) ? cnt[rowb] : 0; nb = nb < CAP ? nb : CAP;
        const unsigned ewa = (lane < na) ? bucket[(size_t)row * CAP + lane] : 0u;
        const unsigned ewb = (lane < nb) ? bucket[(size_t)rowb * CAP + lane] : 0u;
        float a0 = 0.f, a1 = 0.f, b0 = 0.f, b1 = 0.f;
        const int nmax = na > nb ? na : nb;
        const int n16 = (nmax + 15) & ~15;
        for (int e = 0; e < n16; e += 16) {
            unsigned ua[4], ub[4];
            __half2 ga[4], gb[4];
#pragma unroll
            for (int j = 0; j < 4; ++j) {
                int idx = e + j * 4 + h;
                ua[j] = __shfl(ewa, idx);       // idx>=na lanes hold 0 -> col0,val0
                ub[j] = __shfl(ewb, idx);
            }
#pragma unroll
            for (int j = 0; j < 4; ++j) {
                ga[j] = *reinterpret_cast<const __half2*>(support + (size_t)(ua[j] & 0xFFFFu) * D + colbase);
                gb[j] = *reinterpret_cast<const __half2*>(support + (size_t)(ub[j] & 0xFFFFu) * D + colbase);
            }
#pragma unroll
            for (int j = 0; j < 4; ++j) {
                float va = __half2float(__ushort_as_half((unsigned short)(ua[j] >> 16)));
                float vb = __half2float(__ushort_as_half((unsigned short)(ub[j] >> 16)));
                float2 fa = __half22float2(ga[j]);
                float2 fb = __half22float2(gb[j]);
                a0 += va * fa.x; a1 += va * fa.y;
                b0 += vb * fb.x; b1 += vb * fb.y;
            }
        }
        // combine the 4 edge groups
        a0 += __shfl_xor(a0, 16); a1 += __shfl_xor(a1, 16);
        a0 += __shfl_xor(a0, 32); a1 += __shfl_xor(a1, 32);
        b0 += __shfl_xor(b0, 16); b1 += __shfl_xor(b1, 16);
        b0 += __shfl_xor(b0, 32); b1 += __shfl_xor(b1, 32);
        if (h == 0) {
            *reinterpret_cast<float2*>(out + (size_t)row * D + colbase) = make_float2(a0, a1);
            s0 += a0; s1 += a1; q0 += a0 * a0; q1 += a1 * a1;
            if (rowb < N_NODES) {
                *reinterpret_cast<float2*>(out + (size_t)rowb * D + colbase) = make_float2(b0, b1);
                s0 += b0; s1 += b1; q0 += b0 * b0; q1 += b1 * b1;
            }
        }
    }

    if (h == 0) {
        atomicAdd(&lsum[cl * 2 + 0], s0); atomicAdd(&lsum[cl * 2 + 1], s1);
        atomicAdd(&lsq[cl * 2 + 0], q0);  atomicAdd(&lsq[cl * 2 + 1], q1);
    }
    __syncthreads();
    if (tid < SCOLS) {
        atomicAdd(&colsum[slice * SCOLS + tid], lsum[tid]);
        atomicAdd(&colsq[slice * SCOLS + tid], lsq[tid]);
    }
}

__global__ __launch_bounds__(256) void bn_tanh_kernel(float* __restrict__ out,
                                                      const float* __restrict__ colsum,
                                                      const float* __restrict__ colsq,
                                                      const float* __restrict__ gamma,
                                                      const float* __restrict__ beta) {
    __shared__ float scale[D], shift[D];
    const int tid = threadIdx.x;
    if (tid < D) {
        float mean = colsum[tid] * (1.0f / N_NODES);
        float var  = colsq[tid] * (1.0f / N_NODES) - mean * mean;
        float sc   = rsqrtf(var + BN_EPS) * gamma[tid];
        scale[tid] = sc;
        shift[tid] = beta[tid] - mean * sc;
    }
    __syncthreads();
    const int nq = N_NODES * D / 4;
    for (int q = blockIdx.x * 256 + tid; q < nq; q += gridDim.x * 256) {
        float4 v = reinterpret_cast<float4*>(out)[q];
        int c = (q & 31) * 4;
#pragma unroll
        for (int k = 0; k < 4; ++k) {
            float* pv = (&v.x) + k;
            float x = *pv * scale[c + k] + shift[c + k];
            float e = __expf(2.0f * x);
            *pv = 1.0f - 2.0f / (1.0f + e);
        }
        reinterpret_cast<float4*>(out)[q] = v;
    }
}

// ---------------- launch ----------------
extern "C" void kernel_launch(void* const* d_in, const int* in_sizes, int n_in,
                              void* d_out, int out_size, void* d_ws, size_t ws_size,
                              hipStream_t stream) {
    const float* input  = (const float*)d_in[0];
    const int*   arow   = (const int*)d_in[1];
    const int*   acol   = (const int*)d_in[2];
    const float* aval   = (const float*)d_in[3];
    const float* weight = (const float*)d_in[4];
    const float* gamma  = (const float*)d_in[5];
    const float* beta   = (const float*)d_in[6];
    float* out = (float*)d_out;

    __half*   support = (__half*)d_ws;                              // 12.8 MB
    unsigned* bucket  = (unsigned*)(support + (size_t)N_NODES * D); // 12.8 MB
    int*      cnt     = (int*)(bucket + (size_t)N_NODES * CAP);     // 200 KB
    float*    colsum  = (float*)(cnt + N_NODES);                    // 128 (+128 colsq)
    __half*   Ht      = (__half*)(colsum + 2 * D);                  // 32 KB

    zero_kernel<<<196, 256, 0, stream>>>(cnt, colsum);
    buildht_kernel<<<64, 256, 0, stream>>>(weight, Ht);
    scatter_kernel<<<N_EDGES / 256, 256, 0, stream>>>(arow, acol, aval, cnt, bucket);
    gemm_kernel<<<(N_TILES + 3) / 4, 256, 0, stream>>>(input, Ht, support);
    spmm_kernel<<<SPMM_BLOCKS, 256, 0, stream>>>(support, cnt, bucket, out, colsum, colsum + D);
    bn_tanh_kernel<<<2048, 256, 0, stream>>>(out, colsum, colsum + D, gamma, beta);
}

// Round 7
// 125.901 us; speedup vs baseline: 2.1333x; 1.0689x over previous
//
#include <hip/hip_runtime.h>
#include <hip/hip_fp16.h>
#include <math.h>

#define N_NODES 50000
#define N_EDGES 800000
#define D 128
#define BN_EPS 1e-5f
#define N_TILES 3125   // 50000 / 16
#define CAP 64         // max degree capacity (Poisson(16); P(deg>64) ~ 1e-19)
#define SPMM_BLOCKS 2048
#define SCOLS 32       // columns per XCD-pinned slice (3.2 MB fp16 -> fits 4 MiB L2)
#define RROWS 6250     // N_NODES / 8: rows per XCD group in scatter

typedef __attribute__((ext_vector_type(8))) _Float16 half8;
typedef __attribute__((ext_vector_type(4))) float floatx4;

// ---------------- octonion Hamilton tables ----------------
__device__ __constant__ int OCT_C[8][8] = {
    {0,1,2,3,4,5,6,7},
    {1,0,3,2,5,4,7,6},
    {2,3,0,1,6,7,4,5},
    {3,2,1,0,7,6,5,4},
    {4,5,6,7,0,1,2,3},
    {5,4,7,6,1,0,3,2},
    {6,7,4,5,2,3,0,1},
    {7,6,5,4,3,2,1,0}};
__device__ __constant__ float OCT_S[8][8] = {
    { 1,-1,-1,-1,-1,-1,-1,-1},
    { 1, 1,-1, 1,-1, 1, 1,-1},
    { 1, 1, 1,-1,-1,-1, 1, 1},
    { 1,-1, 1, 1,-1, 1,-1, 1},
    { 1, 1, 1, 1, 1,-1,-1,-1},
    { 1,-1, 1,-1, 1, 1, 1,-1},
    { 1,-1,-1, 1, 1,-1, 1, 1},
    { 1, 1,-1,-1, 1, 1,-1, 1}};

// ---------------- kernels ----------------

__global__ void zero_kernel(int* __restrict__ cnt, float* __restrict__ stats) {
    int i = blockIdx.x * 256 + threadIdx.x;
    if (i < N_NODES) cnt[i] = 0;
    if (i < 2 * D) stats[i] = 0.0f;
}

// Ht[col][k] = H[k][col] in fp16 (transposed Hamilton, 32 KB)
__global__ void buildht_kernel(const float* __restrict__ W, __half* __restrict__ Ht) {
    int idx = blockIdx.x * 256 + threadIdx.x;   // 16384
    int ccol = idx >> 7, k = idx & 127;
    int i = k >> 4, kw = k & 15, j = ccol >> 4, m = ccol & 15;
    Ht[idx] = __float2half(OCT_S[j][i] * W[kw * D + OCT_C[j][i] * 16 + m]);
}

// XCD-pinned bucket scatter: group g = blockIdx&7 owns rows [g*RROWS,(g+1)*RROWS).
// Its bucket slice (1.6 MB) + cnt slice stay L2-resident on that XCD, so the
// 64B bucket lines fill completely before eviction (kills write amplification).
__global__ __launch_bounds__(256) void scatter_kernel(const int* __restrict__ arow,
                                                      const int* __restrict__ acol,
                                                      const float* __restrict__ aval,
                                                      int* __restrict__ cnt,
                                                      unsigned* __restrict__ bucket) {
    const int g = blockIdx.x & 7;
    const int rank = blockIdx.x >> 3;            // 0..255 within group
    const int r0 = g * RROWS, r1 = r0 + RROWS;
    for (int i = rank * 256 + threadIdx.x; i < N_EDGES; i += (SPMM_BLOCKS / 8) * 256) {
        int r = arow[i];
        if (r >= r0 && r < r1) {
            int slot = atomicAdd(&cnt[r], 1);
            if (slot < CAP) {
                unsigned hv = (unsigned)__half_as_ushort(__float2half(aval[i]));
                bucket[(size_t)r * CAP + slot] = ((unsigned)acol[i] & 0xFFFFu) | (hv << 16);
            }
        }
    }
}

// ---------------- MFMA gemm: support(fp16) = fp16(input) @ Ht^T ----------------
__global__ __launch_bounds__(256) void gemm_kernel(const float* __restrict__ in,
                                                   const __half* __restrict__ Ht,
                                                   __half* __restrict__ support) {
    const int tid = threadIdx.x;
    const int wv = tid >> 6;
    const int lane = tid & 63;
    const int s = lane & 15;
    const int t = lane >> 4;

    half8 b[8][4];
#pragma unroll
    for (int kk = 0; kk < 4; ++kk)
#pragma unroll
        for (int n = 0; n < 8; ++n)
            b[n][kk] = *reinterpret_cast<const half8*>(Ht + (size_t)(16 * n + s) * D + kk * 32 + 8 * t);

    const int tile = blockIdx.x * 4 + wv;
    if (tile >= N_TILES) return;

    const float* ap = in + (size_t)(tile * 16 + s) * D;
    half8 a[4];
#pragma unroll
    for (int kk = 0; kk < 4; ++kk) {
        float4 f0 = *reinterpret_cast<const float4*>(ap + kk * 32 + 8 * t);
        float4 f1 = *reinterpret_cast<const float4*>(ap + kk * 32 + 8 * t + 4);
        a[kk][0] = (_Float16)f0.x; a[kk][1] = (_Float16)f0.y;
        a[kk][2] = (_Float16)f0.z; a[kk][3] = (_Float16)f0.w;
        a[kk][4] = (_Float16)f1.x; a[kk][5] = (_Float16)f1.y;
        a[kk][6] = (_Float16)f1.z; a[kk][7] = (_Float16)f1.w;
    }

    floatx4 acc[8];
#pragma unroll
    for (int n = 0; n < 8; ++n) acc[n] = (floatx4){0.f, 0.f, 0.f, 0.f};
#pragma unroll
    for (int kk = 0; kk < 4; ++kk)
#pragma unroll
        for (int n = 0; n < 8; ++n)
            acc[n] = __builtin_amdgcn_mfma_f32_16x16x32_f16(a[kk], b[n][kk], acc[n], 0, 0, 0);

    __half* sp = support + (size_t)(tile * 16 + 4 * t) * D + s;
#pragma unroll
    for (int r = 0; r < 4; ++r)
#pragma unroll
        for (int n = 0; n < 8; ++n)
            sp[(size_t)r * D + 16 * n] = __float2half(acc[n][r]);
}

// ---------------- XCD-sliced bucket spmm ----------------
__global__ __launch_bounds__(256) void spmm_kernel(const __half* __restrict__ support,
                                                   const int* __restrict__ cnt,
                                                   const unsigned* __restrict__ bucket,
                                                   float* __restrict__ out,
                                                   float* __restrict__ colsum,
                                                   float* __restrict__ colsq) {
    const int tid = threadIdx.x;
    const int lane = tid & 63;
    const int wv = tid >> 6;
    const int h = lane >> 4;          // edge group 0..3
    const int cl = lane & 15;         // column lane
    const int b = blockIdx.x;
    const int slice = (b & 7) >> 1;
    const int rank = ((b >> 3) << 1) | (b & 1);   // 0..511 within slice
    const int nrank = SPMM_BLOCKS >> 2;           // 512
    const int colbase = slice * SCOLS + cl * 2;

    __shared__ float lsum[SCOLS], lsq[SCOLS];
    if (tid < SCOLS) { lsum[tid] = 0.f; lsq[tid] = 0.f; }
    __syncthreads();

    float s0 = 0.f, s1 = 0.f, q0 = 0.f, q1 = 0.f;

    for (int row = rank * 8 + wv * 2; row < N_NODES; row += nrank * 8) {
        const int rowb = row + 1;
        int na = cnt[row]; na = na < CAP ? na : CAP;
        int nb = (rowb < N_NODES) ? cnt[rowb] : 0; nb = nb < CAP ? nb : CAP;
        const unsigned ewa = (lane < na) ? bucket[(size_t)row * CAP + lane] : 0u;
        const unsigned ewb = (lane < nb) ? bucket[(size_t)rowb * CAP + lane] : 0u;
        float a0 = 0.f, a1 = 0.f, b0 = 0.f, b1 = 0.f;
        const int nmax = na > nb ? na : nb;
        const int n16 = (nmax + 15) & ~15;
        for (int e = 0; e < n16; e += 16) {
            unsigned ua[4], ub[4];
            __half2 ga[4], gb[4];
#pragma unroll
            for (int j = 0; j < 4; ++j) {
                int idx = e + j * 4 + h;
                ua[j] = __shfl(ewa, idx);       // idx>=na lanes hold 0 -> col0,val0
                ub[j] = __shfl(ewb, idx);
            }
#pragma unroll
            for (int j = 0; j < 4; ++j) {
                ga[j] = *reinterpret_cast<const __half2*>(support + (size_t)(ua[j] & 0xFFFFu) * D + colbase);
                gb[j] = *reinterpret_cast<const __half2*>(support + (size_t)(ub[j] & 0xFFFFu) * D + colbase);
            }
#pragma unroll
            for (int j = 0; j < 4; ++j) {
                float va = __half2float(__ushort_as_half((unsigned short)(ua[j] >> 16)));
                float vb = __half2float(__ushort_as_half((unsigned short)(ub[j] >> 16)));
                float2 fa = __half22float2(ga[j]);
                float2 fb = __half22float2(gb[j]);
                a0 += va * fa.x; a1 += va * fa.y;
                b0 += vb * fb.x; b1 += vb * fb.y;
            }
        }
        a0 += __shfl_xor(a0, 16); a1 += __shfl_xor(a1, 16);
        a0 += __shfl_xor(a0, 32); a1 += __shfl_xor(a1, 32);
        b0 += __shfl_xor(b0, 16); b1 += __shfl_xor(b1, 16);
        b0 += __shfl_xor(b0, 32); b1 += __shfl_xor(b1, 32);
        if (h == 0) {
            *reinterpret_cast<float2*>(out + (size_t)row * D + colbase) = make_float2(a0, a1);
            s0 += a0; s1 += a1; q0 += a0 * a0; q1 += a1 * a1;
            if (rowb < N_NODES) {
                *reinterpret_cast<float2*>(out + (size_t)rowb * D + colbase) = make_float2(b0, b1);
                s0 += b0; s1 += b1; q0 += b0 * b0; q1 += b1 * b1;
            }
        }
    }

    if (h == 0) {
        atomicAdd(&lsum[cl * 2 + 0], s0); atomicAdd(&lsum[cl * 2 + 1], s1);
        atomicAdd(&lsq[cl * 2 + 0], q0);  atomicAdd(&lsq[cl * 2 + 1], q1);
    }
    __syncthreads();
    if (tid < SCOLS) {
        atomicAdd(&colsum[slice * SCOLS + tid], lsum[tid]);
        atomicAdd(&colsq[slice * SCOLS + tid], lsq[tid]);
    }
}

__global__ __launch_bounds__(256) void bn_tanh_kernel(float* __restrict__ out,
                                                      const float* __restrict__ colsum,
                                                      const float* __restrict__ colsq,
                                                      const float* __restrict__ gamma,
                                                      const float* __restrict__ beta) {
    __shared__ float scale[D], shift[D];
    const int tid = threadIdx.x;
    if (tid < D) {
        float mean = colsum[tid] * (1.0f / N_NODES);
        float var  = colsq[tid] * (1.0f / N_NODES) - mean * mean;
        float sc   = rsqrtf(var + BN_EPS) * gamma[tid];
        scale[tid] = sc;
        shift[tid] = beta[tid] - mean * sc;
    }
    __syncthreads();
    const int nq = N_NODES * D / 4;
    for (int q = blockIdx.x * 256 + tid; q < nq; q += gridDim.x * 256) {
        float4 v = reinterpret_cast<float4*>(out)[q];
        int c = (q & 31) * 4;
#pragma unroll
        for (int k = 0; k < 4; ++k) {
            float* pv = (&v.x) + k;
            float x = *pv * scale[c + k] + shift[c + k];
            float e = __expf(2.0f * x);
            *pv = 1.0f - 2.0f / (1.0f + e);
        }
        reinterpret_cast<float4*>(out)[q] = v;
    }
}

// ---------------- launch ----------------
extern "C" void kernel_launch(void* const* d_in, const int* in_sizes, int n_in,
                              void* d_out, int out_size, void* d_ws, size_t ws_size,
                              hipStream_t stream) {
    const float* input  = (const float*)d_in[0];
    const int*   arow   = (const int*)d_in[1];
    const int*   acol   = (const int*)d_in[2];
    const float* aval   = (const float*)d_in[3];
    const float* weight = (const float*)d_in[4];
    const float* gamma  = (const float*)d_in[5];
    const float* beta   = (const float*)d_in[6];
    float* out = (float*)d_out;

    __half*   support = (__half*)d_ws;                              // 12.8 MB
    unsigned* bucket  = (unsigned*)(support + (size_t)N_NODES * D); // 12.8 MB
    int*      cnt     = (int*)(bucket + (size_t)N_NODES * CAP);     // 200 KB
    float*    colsum  = (float*)(cnt + N_NODES);                    // 128 (+128 colsq)
    __half*   Ht      = (__half*)(colsum + 2 * D);                  // 32 KB

    zero_kernel<<<196, 256, 0, stream>>>(cnt, colsum);
    buildht_kernel<<<64, 256, 0, stream>>>(weight, Ht);
    scatter_kernel<<<SPMM_BLOCKS, 256, 0, stream>>>(arow, acol, aval, cnt, bucket);
    gemm_kernel<<<(N_TILES + 3) / 4, 256, 0, stream>>>(input, Ht, support);
    spmm_kernel<<<SPMM_BLOCKS, 256, 0, stream>>>(support, cnt, bucket, out, colsum, colsum + D);
    bn_tanh_kernel<<<2048, 256, 0, stream>>>(out, colsum, colsum + D, gamma, beta);
}